// Round 4
// baseline (96.994 us; speedup 1.0000x reference)
//
#include <hip/hip_runtime.h>
#include <hip/hip_bf16.h>

// HGT_DNF conjunction layer, folded form (idx = [0..52,0..52] => W[n]=weights[n%53]).
// out[b,o] = sum_j w[j,o]*xm[b,j]                               (fp32, fmac)
//          - sum_j (d*|w[j,o]|)*s[b,j] + max_j (d*|w[j,o]|)*m[b,j]  (packed f16, d=0.01)
//
// R4 change: per-(b,j) scalars are staged into LDS per block and read as
// wave-uniform ds_read_b128 broadcasts. Rationale: SMEM (s_load) completions
// are out-of-order -> LLVM emits lgkmcnt(0) before every use, serializing the
// j-loop on L2 latency; DS is in-order -> fine-grained lgkmcnt(N), pipelinable.
// TBB 16->8 doubles occupancy to 4 waves/SIMD.

typedef _Float16 h2 __attribute__((ext_vector_type(2)));
typedef unsigned int u32;

#define B_TOTAL 4096
#define N_PRED 106
#define K_FOLD 53
#define OUT_N 1024
#define DELTA_C 0.01f
#define PREP_ROWS 64
#define TBB 8     // b-rows per thread/block in main kernel

static __device__ __forceinline__ h2 pk2(float a, float b) {
    return __builtin_bit_cast(h2, __builtin_amdgcn_cvt_pkrtz(a, b));
}

__global__ __launch_bounds__(256) void prep_kernel(
    const float* __restrict__ x,
    float* __restrict__ xmT,   // [53][4096] f32
    u32* __restrict__ sdupT,   // [53][4096] (f16,f16) duplicated
    u32* __restrict__ mdupT) { // [53][4096] (f16,f16) duplicated
    __shared__ float lx[PREP_ROWS * N_PRED];
    const int b0 = blockIdx.x * PREP_ROWS;
    const int t = threadIdx.x;

    const float* src = x + (size_t)b0 * N_PRED;
    for (int i = t; i < PREP_ROWS * N_PRED; i += 256) lx[i] = src[i];
    __syncthreads();

    for (int id = t; id < K_FOLD * PREP_ROWS; id += 256) {
        int j = id >> 6;
        int r = id & 63;
        float xlo = lx[r * N_PRED + j];
        float xhi = lx[r * N_PRED + K_FOLD + j];
        float alo = fabsf(xlo), ahi = fabsf(xhi);
        float xmv = (xlo >= -1.f ? xlo : 0.f) + (xhi >= -1.f ? xhi : 0.f);
        float sv = alo + ahi;
        float mv = fmaxf(alo, ahi);
        size_t off = (size_t)j * B_TOTAL + b0 + r;
        xmT[off] = xmv;
        sdupT[off] = __builtin_bit_cast(u32, pk2(sv, sv));
        mdupT[off] = __builtin_bit_cast(u32, pk2(mv, mv));
    }
}

__global__ __launch_bounds__(256) void conj_kernel(
    const float* __restrict__ w,     // [54][1024] f32 (rows 0..52 used)
    const float* __restrict__ xmT,   // [53][4096]
    const u32* __restrict__ sdupT,
    const u32* __restrict__ mdupT,
    float* __restrict__ out) {       // [4096][1024]
    __shared__ float xmL[K_FOLD * TBB];
    __shared__ u32 sL[K_FOLD * TBB];
    __shared__ u32 mL[K_FOLD * TBB];

    const int t = threadIdx.x;
    const int opair = blockIdx.x * 256 + t;   // 0..511; lane owns 2 o's
    const int b0 = blockIdx.y * TBB;

    // Stage this block's 8 b-rows of xm/s/m for all 53 j into LDS (coalesced
    // in groups of 8 consecutive addresses).
    for (int id = t; id < K_FOLD * TBB; id += 256) {
        int j = id >> 3;
        int r = id & 7;
        size_t g = (size_t)j * B_TOTAL + b0 + r;
        xmL[id] = xmT[g];
        sL[id] = sdupT[g];
        mL[id] = mdupT[g];
    }
    __syncthreads();

    float accO0[TBB], accO1[TBB];
    h2 accS[TBB], accM[TBB];
    const h2 hz = {(_Float16)0.f, (_Float16)0.f};
#pragma unroll
    for (int r = 0; r < TBB; ++r) {
        accO0[r] = 0.f; accO1[r] = 0.f;
        accS[r] = hz; accM[r] = hz;
    }

    const float2* wp = (const float2*)w;
#pragma unroll 2
    for (int j = 0; j < K_FOLD; ++j) {
        float2 wv = wp[j * (OUT_N / 2) + opair];
        h2 awd = pk2(DELTA_C * fabsf(wv.x), DELTA_C * fabsf(wv.y));
        h2 gn = -awd;

        // Wave-uniform broadcast reads, vectorized to ds_read_b128.
        float4 xa = *(const float4*)&xmL[j * TBB];
        float4 xb = *(const float4*)&xmL[j * TBB + 4];
        uint4 sa = *(const uint4*)&sL[j * TBB];
        uint4 sb = *(const uint4*)&sL[j * TBB + 4];
        uint4 ma = *(const uint4*)&mL[j * TBB];
        uint4 mb = *(const uint4*)&mL[j * TBB + 4];
        float xmv[TBB] = {xa.x, xa.y, xa.z, xa.w, xb.x, xb.y, xb.z, xb.w};
        u32 sv[TBB] = {sa.x, sa.y, sa.z, sa.w, sb.x, sb.y, sb.z, sb.w};
        u32 mv[TBB] = {ma.x, ma.y, ma.z, ma.w, mb.x, mb.y, mb.z, mb.w};

#pragma unroll
        for (int r = 0; r < TBB; ++r) {
            accO0[r] = fmaf(xmv[r], wv.x, accO0[r]);   // v_fmac_f32
            accO1[r] = fmaf(xmv[r], wv.y, accO1[r]);   // v_fmac_f32
            accS[r] = gn * __builtin_bit_cast(h2, sv[r]) + accS[r];  // v_pk_fma_f16
            accM[r] = __builtin_elementwise_max(
                accM[r], awd * __builtin_bit_cast(h2, mv[r]));       // pk_mul+pk_max
        }
    }

#pragma unroll
    for (int r = 0; r < TBB; ++r) {
        float o0 = accO0[r] + (float)accS[r].x + (float)accM[r].x;
        float o1 = accO1[r] + (float)accS[r].y + (float)accM[r].y;
        ((float2*)(out + (size_t)(b0 + r) * OUT_N))[opair] = make_float2(o0, o1);
    }
}

extern "C" void kernel_launch(void* const* d_in, const int* in_sizes, int n_in,
                              void* d_out, int out_size, void* d_ws, size_t ws_size,
                              hipStream_t stream) {
    const float* x = (const float*)d_in[0];        // [4096,106]
    const float* weights = (const float*)d_in[1];  // [54,1024]
    float* out = (float*)d_out;                    // [4096,1024]

    float* xmT = (float*)d_ws;                                   // 868 KiB
    u32* sdupT = (u32*)(xmT + (size_t)K_FOLD * B_TOTAL);         // 868 KiB
    u32* mdupT = sdupT + (size_t)K_FOLD * B_TOTAL;               // 868 KiB

    prep_kernel<<<dim3(B_TOTAL / PREP_ROWS), dim3(256), 0, stream>>>(
        x, xmT, sdupT, mdupT);
    conj_kernel<<<dim3(OUT_N / 512, B_TOTAL / TBB), dim3(256), 0, stream>>>(
        weights, xmT, sdupT, mdupT, out);
}

// Round 5
// 96.269 us; speedup vs baseline: 1.0075x; 1.0075x over previous
//
#include <hip/hip_runtime.h>
#include <hip/hip_bf16.h>

// HGT_DNF folded (idx=[0..52,0..52] => W[n]=weights[n%53]).
// out[b,o] = sum_j w*xm + sum_j |w|*(-d*s) + max_j |w|*(d*m),  all packed f16.
// R5: weights resident in VGPRs (53 pk-pairs/lane, loaded once); per-(b,j)
// dup-f16 streams read as wave-uniform s_load chunks (b uniform via
// readfirstlane) -> SGPR operands, zero LDS, zero per-visit VALU load cost.

typedef _Float16 h2 __attribute__((ext_vector_type(2)));
typedef unsigned int u32;

#define B_TOTAL 4096
#define N_PRED 106
#define K_FOLD 53
#define JP 56          // j padded to 7 chunks of 8
#define NCH 7
#define OUT_N 1024
#define DELTA_C 0.01f
#define PREP_ROWS 32

static __device__ __forceinline__ h2 pk2(float a, float b) {
    return __builtin_bit_cast(h2, __builtin_amdgcn_cvt_pkrtz(a, b));
}
static __device__ __forceinline__ u32 pkdup(float v) {
    return __builtin_bit_cast(u32, pk2(v, v));
}
static __device__ __forceinline__ h2 habs(h2 v) {
    return __builtin_bit_cast(h2, __builtin_bit_cast(u32, v) & 0x7FFF7FFFu);
}

__global__ __launch_bounds__(256) void prep_kernel(
    const float* __restrict__ x,
    u32* __restrict__ xmd,   // [4096][56] dup-f16 xm
    u32* __restrict__ snd,   // [4096][56] dup-f16 (-d*s)
    u32* __restrict__ mdd) { // [4096][56] dup-f16 (d*m)
    __shared__ float lx[PREP_ROWS * N_PRED];
    const int b0 = blockIdx.x * PREP_ROWS;
    const int t = threadIdx.x;
    const float* src = x + (size_t)b0 * N_PRED;
    for (int i = t; i < PREP_ROWS * N_PRED; i += 256) lx[i] = src[i];
    __syncthreads();
    for (int id = t; id < PREP_ROWS * JP; id += 256) {
        int r = id / JP;
        int j = id - r * JP;
        float xmv = 0.f, sn = 0.f, mv = 0.f;
        if (j < K_FOLD) {
            float xlo = lx[r * N_PRED + j];
            float xhi = lx[r * N_PRED + K_FOLD + j];
            float alo = fabsf(xlo), ahi = fabsf(xhi);
            xmv = (xlo >= -1.f ? xlo : 0.f) + (xhi >= -1.f ? xhi : 0.f);
            sn = -DELTA_C * (alo + ahi);
            mv = DELTA_C * fmaxf(alo, ahi);
        }
        size_t off = (size_t)(b0 + r) * JP + j;
        xmd[off] = pkdup(xmv);
        snd[off] = pkdup(sn);
        mdd[off] = pkdup(mv);
    }
}

__global__ __launch_bounds__(256) void conj_kernel(
    const float* __restrict__ w,     // [54][1024] f32 (rows 0..52 used)
    const u32* __restrict__ xmd,
    const u32* __restrict__ snd,
    const u32* __restrict__ mdd,
    float* __restrict__ out) {       // [4096][1024]
    const int t = threadIdx.x;
    const int lane = t & 63;
    // readfirstlane: make the wave id (and thus b) provably wave-uniform so
    // the stream loads scalarize to s_load (SGPR-resident, scalar pipe).
    const int wv = __builtin_amdgcn_readfirstlane(t >> 6);
    const int ostrip = blockIdx.x & 7;   // 8 strips of 128 o
    const int bg = blockIdx.x >> 3;      // 128 groups of 32 b
    const int o0 = ostrip * 128 + lane * 2;
    const int bbase = bg * 32 + wv * 8;  // 8 b per wave

    // Weights resident in VGPRs: 56 packed f16 o-pairs (rows 53..55 = 0).
    h2 wd[JP];
    const h2 hz = {(_Float16)0.f, (_Float16)0.f};
#pragma unroll
    for (int j = 0; j < JP; ++j) {
        h2 v = hz;
        if (j < K_FOLD) {
            float2 t2 = *(const float2*)(w + j * OUT_N + o0);  // coalesced, L2
            v = pk2(t2.x, t2.y);
        }
        wd[j] = v;
    }

#pragma unroll 1
    for (int bi = 0; bi < 8; ++bi) {
        const int b = bbase + bi;  // wave-uniform
        const u32* px = xmd + (size_t)b * JP;
        const u32* ps = snd + (size_t)b * JP;
        const u32* pm = mdd + (size_t)b * JP;

        h2 accOa = hz, accOb = hz, accM = hz;

        uint4 cx0 = *(const uint4*)(px + 0), cx1 = *(const uint4*)(px + 4);
        uint4 cs0 = *(const uint4*)(ps + 0), cs1 = *(const uint4*)(ps + 4);
        uint4 cm0 = *(const uint4*)(pm + 0), cm1 = *(const uint4*)(pm + 4);

#pragma unroll
        for (int jc = 0; jc < NCH; ++jc) {
            uint4 nx0, nx1, ns0, ns1, nm0, nm1;
            if (jc + 1 < NCH) {
                nx0 = *(const uint4*)(px + 8 * (jc + 1));
                nx1 = *(const uint4*)(px + 8 * (jc + 1) + 4);
                ns0 = *(const uint4*)(ps + 8 * (jc + 1));
                ns1 = *(const uint4*)(ps + 8 * (jc + 1) + 4);
                nm0 = *(const uint4*)(pm + 8 * (jc + 1));
                nm1 = *(const uint4*)(pm + 8 * (jc + 1) + 4);
            }
            u32 xs[8] = {cx0.x, cx0.y, cx0.z, cx0.w, cx1.x, cx1.y, cx1.z, cx1.w};
            u32 ss[8] = {cs0.x, cs0.y, cs0.z, cs0.w, cs1.x, cs1.y, cs1.z, cs1.w};
            u32 ms[8] = {cm0.x, cm0.y, cm0.z, cm0.w, cm1.x, cm1.y, cm1.z, cm1.w};
#pragma unroll
            for (int k = 0; k < 8; ++k) {
                h2 wv2 = wd[jc * 8 + k];
                h2 aw = habs(wv2);                      // v_and_b32
                accOa = wv2 * __builtin_bit_cast(h2, xs[k]) + accOa;  // pk_fma
                accOb = aw * __builtin_bit_cast(h2, ss[k]) + accOb;   // pk_fma
                accM = __builtin_elementwise_max(
                    accM, aw * __builtin_bit_cast(h2, ms[k]));        // pk_mul+max
            }
            if (jc + 1 < NCH) {
                cx0 = nx0; cx1 = nx1; cs0 = ns0; cs1 = ns1; cm0 = nm0; cm1 = nm1;
            }
        }

        float2 r;
        r.x = (float)accOa.x + (float)accOb.x + (float)accM.x;
        r.y = (float)accOa.y + (float)accOb.y + (float)accM.y;
        *(float2*)(out + (size_t)b * OUT_N + o0) = r;
    }
}

extern "C" void kernel_launch(void* const* d_in, const int* in_sizes, int n_in,
                              void* d_out, int out_size, void* d_ws, size_t ws_size,
                              hipStream_t stream) {
    const float* x = (const float*)d_in[0];        // [4096,106]
    const float* weights = (const float*)d_in[1];  // [54,1024]
    float* out = (float*)d_out;                    // [4096,1024]

    u32* xmd = (u32*)d_ws;                          // 4096*56*4 = 896 KiB each
    u32* snd = xmd + (size_t)B_TOTAL * JP;
    u32* mdd = snd + (size_t)B_TOTAL * JP;

    prep_kernel<<<dim3(B_TOTAL / PREP_ROWS), dim3(256), 0, stream>>>(
        x, xmd, snd, mdd);
    conj_kernel<<<dim3(8 * (B_TOTAL / 32)), dim3(256), 0, stream>>>(
        weights, xmd, snd, mdd, out);
}